// Round 1
// baseline (2819.302 us; speedup 1.0000x reference)
//
#include <hip/hip_runtime.h>
#include <hip/hip_bf16.h>

// MoE SwiGLU: out[t] = sum_k gate[t,k] * W2[e] @ (silu(W1[e] x_t) * (W3[e] x_t))
// Strategy: route -> pad per-expert segments to BM -> bf16 MFMA grouped GEMMs.

#define T_TOK 8192
#define DIM   2560
#define INTER 1664
#define NEXP  16
#define TOPK  6

#define BM 128
#define BN 128
#define BK 64
#define SEG_CAP 8192                       // static per-expert row bound (mean 3072, sigma ~54)
#define MAXROWS (T_TOK*TOPK + NEXP*BM)     // 49152 + 2048 = 51200 padded pair rows

typedef __attribute__((ext_vector_type(4))) float f32x4;
typedef __attribute__((ext_vector_type(8))) short short8;
using bf16 = __hip_bfloat16;

// ---------------- async global->LDS (wave-uniform LDS base + lane*16) ----------
__device__ __forceinline__ void gload_lds16(const void* g, void* l) {
    __builtin_amdgcn_global_load_lds(
        (const __attribute__((address_space(1))) void*)g,
        (__attribute__((address_space(3))) void*)l,
        16, 0, 0);
}

// ---------------- fp32 -> bf16 bulk convert (vectorized, grid-stride) ----------
__global__ __launch_bounds__(256) void cvt_f32_to_bf16(const float* __restrict__ src,
                                                       bf16* __restrict__ dst, long n8) {
    long stride = (long)gridDim.x * 256;
    for (long i = (long)blockIdx.x * 256 + threadIdx.x; i < n8; i += stride) {
        long b = i * 8;
        float4 a0 = *reinterpret_cast<const float4*>(src + b);
        float4 a1 = *reinterpret_cast<const float4*>(src + b + 4);
        bf16 t[8];
        t[0] = __float2bfloat16(a0.x); t[1] = __float2bfloat16(a0.y);
        t[2] = __float2bfloat16(a0.z); t[3] = __float2bfloat16(a0.w);
        t[4] = __float2bfloat16(a1.x); t[5] = __float2bfloat16(a1.y);
        t[6] = __float2bfloat16(a1.z); t[7] = __float2bfloat16(a1.w);
        *reinterpret_cast<uint4*>(dst + b) = *reinterpret_cast<uint4*>(t);
    }
}

// ---------------- routing --------------------------------------------------
// detect whether expert_indices arrived as int64 (reference dtype) or int32
__global__ void detect_idx_width(const long long* __restrict__ p, int* __restrict__ flag) {
    __shared__ int ok;
    if (threadIdx.x == 0) ok = 1;
    __syncthreads();
    long long v = p[threadIdx.x];          // 256 entries; safe under either layout
    if (v < 0 || v >= NEXP) atomicAnd(&ok, 0);
    __syncthreads();
    if (threadIdx.x == 0) *flag = ok;      // 1 => int64 layout
}

__device__ __forceinline__ int load_eidx(const void* eidx, int i, int wide) {
    if (wide) return (int)((const long long*)eidx)[i];
    return ((const int*)eidx)[i];
}

__global__ void route_count(const void* __restrict__ eidx, const int* __restrict__ wideflag,
                            int* __restrict__ counts) {
    int i = blockIdx.x * 256 + threadIdx.x;
    if (i < T_TOK * TOPK) {
        int e = load_eidx(eidx, i, *wideflag) & (NEXP - 1);
        atomicAdd(&counts[e], 1);
    }
}

__global__ void route_scan(const int* __restrict__ counts, int* __restrict__ poff) {
    if (threadIdx.x == 0) {
        int s = 0;
        for (int e = 0; e < NEXP; ++e) { poff[e] = s; s += (counts[e] + BM - 1) & ~(BM - 1); }
        poff[NEXP] = s;
    }
}

__global__ void route_scatter(const void* __restrict__ eidx, const float* __restrict__ wts,
                              const int* __restrict__ wideflag,
                              const int* __restrict__ poff, int* __restrict__ cursors,
                              int* __restrict__ token_ids, float* __restrict__ gate) {
    int i = blockIdx.x * 256 + threadIdx.x;
    if (i < T_TOK * TOPK) {
        int e = load_eidx(eidx, i, *wideflag) & (NEXP - 1);
        int p = poff[e] + atomicAdd(&cursors[e], 1);
        token_ids[p] = i / TOPK;
        gate[p] = wts[i];
    }
}

// ---------------- GEMM1: H = silu(X W1^T) * (X W3^T) * gate   (bf16 MFMA) ----
__global__ __launch_bounds__(256, 2) void gemm1_swiglu(
    const bf16* __restrict__ xb, const bf16* __restrict__ wb1, const bf16* __restrict__ wb3,
    const int* __restrict__ token_ids, const float* __restrict__ gate,
    const int* __restrict__ counts, const int* __restrict__ poff,
    bf16* __restrict__ H)
{
    const int e = blockIdx.z;
    const int segbase = poff[e];
    const int padded  = poff[e + 1] - segbase;
    const int m0 = blockIdx.y * BM;
    if (m0 >= padded) return;                 // dead block (static grid over-provision)
    const int cnt = counts[e];
    const int n0 = blockIdx.x * BN;

    __shared__ bf16 As[BM][BK];               // 16 KB, row = 128 B (m97 layout)
    __shared__ bf16 B1s[BN][BK];
    __shared__ bf16 B3s[BN][BK];
    __shared__ float gs[BM];

    const int tid = threadIdx.x;
    const int lane = tid & 63;
    const int w = tid >> 6;                   // 4 waves, 2x2 quadrants of 64x64
    const int wm = w >> 1, wn = w & 1;

    if (tid < BM) gs[tid] = gate[segbase + m0 + tid];   // pads are 0 (memset)

    // per-lane gathered A row base pointers (token ids constant across K-steps)
    const bf16* asrc[4];
#pragma unroll
    for (int c = 0; c < 4; ++c) {
        int row = w * 32 + c * 8 + (lane >> 3);
        int pr = m0 + row; if (pr >= cnt) pr = cnt - 1;     // clamp pad rows
        int tok = token_ids[segbase + pr];
        asrc[c] = xb + (size_t)tok * DIM + (lane & 7) * 8;
    }
    const bf16* b1base = wb1 + (size_t)e * INTER * DIM;
    const bf16* b3base = wb3 + (size_t)e * INTER * DIM;

    f32x4 acc1[4][4] = {{}};
    f32x4 acc3[4][4] = {{}};

    for (int kk = 0; kk < DIM / BK; ++kk) {
        const int k0 = kk * BK;
#pragma unroll
        for (int c = 0; c < 4; ++c) {
            gload_lds16(asrc[c] + k0, &As[w * 32 + c * 8][0]);
            int row = w * 32 + c * 8 + (lane >> 3);
            gload_lds16(b1base + (size_t)(n0 + row) * DIM + k0 + (lane & 7) * 8,
                        &B1s[w * 32 + c * 8][0]);
            gload_lds16(b3base + (size_t)(n0 + row) * DIM + k0 + (lane & 7) * 8,
                        &B3s[w * 32 + c * 8][0]);
        }
        __syncthreads();                       // compiler drains vmcnt before barrier
#pragma unroll
        for (int k2 = 0; k2 < 2; ++k2) {
            short8 av[4], b1v[4], b3v[4];
#pragma unroll
            for (int i = 0; i < 4; ++i)
                av[i] = *reinterpret_cast<const short8*>(
                    &As[wm * 64 + i * 16 + (lane & 15)][k2 * 32 + (lane >> 4) * 8]);
#pragma unroll
            for (int j = 0; j < 4; ++j) {
                b1v[j] = *reinterpret_cast<const short8*>(
                    &B1s[wn * 64 + j * 16 + (lane & 15)][k2 * 32 + (lane >> 4) * 8]);
                b3v[j] = *reinterpret_cast<const short8*>(
                    &B3s[wn * 64 + j * 16 + (lane & 15)][k2 * 32 + (lane >> 4) * 8]);
            }
#pragma unroll
            for (int i = 0; i < 4; ++i)
#pragma unroll
                for (int j = 0; j < 4; ++j) {
                    acc1[i][j] = __builtin_amdgcn_mfma_f32_16x16x32_bf16(av[i], b1v[j], acc1[i][j], 0, 0, 0);
                    acc3[i][j] = __builtin_amdgcn_mfma_f32_16x16x32_bf16(av[i], b3v[j], acc3[i][j], 0, 0, 0);
                }
        }
        __syncthreads();
    }

    // epilogue: h = silu(a1)*a3*gate  -> bf16 H (pad rows get gate=0 -> h=0)
#pragma unroll
    for (int i = 0; i < 4; ++i) {
#pragma unroll
        for (int r = 0; r < 4; ++r) {
            int rowl = wm * 64 + i * 16 + (lane >> 4) * 4 + r;  // C/D: row=(l>>4)*4+reg
            float g = gs[rowl];
            size_t rowg = (size_t)(segbase + m0 + rowl);
#pragma unroll
            for (int j = 0; j < 4; ++j) {
                int col = n0 + wn * 64 + j * 16 + (lane & 15);  // C/D: col=l&15
                float a1 = acc1[i][j][r];
                float a3 = acc3[i][j][r];
                float h = (a1 / (1.f + __expf(-a1))) * a3 * g;
                H[rowg * INTER + col] = __float2bfloat16(h);
            }
        }
    }
}

// ---------------- GEMM2: out[tok] += H W2^T  (atomic combine) ----------------
__global__ __launch_bounds__(256, 2) void gemm2_scatter(
    const bf16* __restrict__ H, const bf16* __restrict__ wb2,
    const int* __restrict__ token_ids,
    const int* __restrict__ counts, const int* __restrict__ poff,
    float* __restrict__ out)
{
    const int e = blockIdx.z;
    const int segbase = poff[e];
    const int padded  = poff[e + 1] - segbase;
    const int m0 = blockIdx.y * BM;
    if (m0 >= padded) return;
    const int cnt = counts[e];
    const int n0 = blockIdx.x * BN;

    __shared__ bf16 As[BM][BK];
    __shared__ bf16 Bs[BN][BK];
    __shared__ int tids[BM];

    const int tid = threadIdx.x;
    const int lane = tid & 63;
    const int w = tid >> 6;
    const int wm = w >> 1, wn = w & 1;

    if (tid < BM) tids[tid] = token_ids[segbase + m0 + tid];

    const bf16* b2base = wb2 + (size_t)e * DIM * INTER;

    f32x4 acc[4][4] = {{}};

    for (int kk = 0; kk < INTER / BK; ++kk) {
        const int k0 = kk * BK;
#pragma unroll
        for (int c = 0; c < 4; ++c) {
            int row = w * 32 + c * 8 + (lane >> 3);
            gload_lds16(H + (size_t)(segbase + m0 + row) * INTER + k0 + (lane & 7) * 8,
                        &As[w * 32 + c * 8][0]);
            gload_lds16(b2base + (size_t)(n0 + row) * INTER + k0 + (lane & 7) * 8,
                        &Bs[w * 32 + c * 8][0]);
        }
        __syncthreads();
#pragma unroll
        for (int k2 = 0; k2 < 2; ++k2) {
            short8 av[4], bv[4];
#pragma unroll
            for (int i = 0; i < 4; ++i)
                av[i] = *reinterpret_cast<const short8*>(
                    &As[wm * 64 + i * 16 + (lane & 15)][k2 * 32 + (lane >> 4) * 8]);
#pragma unroll
            for (int j = 0; j < 4; ++j)
                bv[j] = *reinterpret_cast<const short8*>(
                    &Bs[wn * 64 + j * 16 + (lane & 15)][k2 * 32 + (lane >> 4) * 8]);
#pragma unroll
            for (int i = 0; i < 4; ++i)
#pragma unroll
                for (int j = 0; j < 4; ++j)
                    acc[i][j] = __builtin_amdgcn_mfma_f32_16x16x32_bf16(av[i], bv[j], acc[i][j], 0, 0, 0);
        }
        __syncthreads();
    }

#pragma unroll
    for (int i = 0; i < 4; ++i) {
#pragma unroll
        for (int r = 0; r < 4; ++r) {
            int rowl = wm * 64 + i * 16 + (lane >> 4) * 4 + r;
            if (m0 + rowl < cnt) {
                int tok = tids[rowl];
#pragma unroll
                for (int j = 0; j < 4; ++j) {
                    int col = n0 + wn * 64 + j * 16 + (lane & 15);
                    atomicAdd(&out[(size_t)tok * DIM + col], acc[i][j][r]);
                }
            }
        }
    }
}

// ---------------- launch -----------------------------------------------------
extern "C" void kernel_launch(void* const* d_in, const int* in_sizes, int n_in,
                              void* d_out, int out_size, void* d_ws, size_t ws_size,
                              hipStream_t stream)
{
    const float* x    = (const float*)d_in[0];
    const void*  eidx = d_in[1];                 // int32 or int64, detected on device
    const float* ewts = (const float*)d_in[2];
    const float* w1   = (const float*)d_in[3];
    const float* w2   = (const float*)d_in[4];
    const float* w3   = (const float*)d_in[5];
    float* out = (float*)d_out;

    char* ws = (char*)d_ws;
    size_t off = 0;
    auto alloc = [&](size_t bytes) -> char* {
        char* p = ws + off; off += (bytes + 255) & ~(size_t)255; return p;
    };
    bf16* xb    = (bf16*)alloc((size_t)T_TOK * DIM * 2);          //  42.0 MB
    bf16* wb1   = (bf16*)alloc((size_t)NEXP * INTER * DIM * 2);   // 136.3 MB
    bf16* wb3   = (bf16*)alloc((size_t)NEXP * INTER * DIM * 2);   // 136.3 MB
    bf16* wb2   = (bf16*)alloc((size_t)NEXP * DIM * INTER * 2);   // 136.3 MB
    bf16* H     = (bf16*)alloc((size_t)MAXROWS * INTER * 2);      // 170.4 MB
    int*  token_ids = (int*)alloc(MAXROWS * 4);
    float* gate     = (float*)alloc(MAXROWS * 4);
    int*  counts    = (int*)alloc(64);
    int*  cursors   = (int*)alloc(64);
    int*  poff      = (int*)alloc(68);
    int*  wideflag  = (int*)alloc(64);
    if (off > ws_size) return;   // ws too small: leave out poisoned -> loud failure

    hipMemsetAsync(out, 0, (size_t)T_TOK * DIM * 4, stream);
    hipMemsetAsync(token_ids, 0, MAXROWS * 4, stream);
    hipMemsetAsync(gate, 0, MAXROWS * 4, stream);
    hipMemsetAsync(counts, 0, 64, stream);
    hipMemsetAsync(cursors, 0, 64, stream);

    detect_idx_width<<<1, 256, 0, stream>>>((const long long*)eidx, wideflag);

    long n8x = (long)T_TOK * DIM / 8;
    long n8w = (long)NEXP * INTER * DIM / 8;
    cvt_f32_to_bf16<<<2048, 256, 0, stream>>>(x,  xb,  n8x);
    cvt_f32_to_bf16<<<2048, 256, 0, stream>>>(w1, wb1, n8w);
    cvt_f32_to_bf16<<<2048, 256, 0, stream>>>(w3, wb3, n8w);
    cvt_f32_to_bf16<<<2048, 256, 0, stream>>>(w2, wb2, n8w);

    int nblk = (T_TOK * TOPK + 255) / 256;
    route_count  <<<nblk, 256, 0, stream>>>(eidx, wideflag, counts);
    route_scan   <<<1, 64, 0, stream>>>(counts, poff);
    route_scatter<<<nblk, 256, 0, stream>>>(eidx, ewts, wideflag, poff, cursors, token_ids, gate);

    gemm1_swiglu <<<dim3(INTER / BN, SEG_CAP / BM, NEXP), 256, 0, stream>>>(
        xb, wb1, wb3, token_ids, gate, counts, poff, H);
    gemm2_scatter<<<dim3(DIM / BN, SEG_CAP / BM, NEXP), 256, 0, stream>>>(
        H, wb2, token_ids, counts, poff, out);
}